// Round 17
// baseline (2716.400 us; speedup 1.0000x reference)
//
#include <hip/hip_runtime.h>

// LSTM: B=256, T=512, I=64, H=512, G=4H=2048.
// gates = W @ [h; x], W = [R | kernel^T], K = 576.
// Persistent kernel: 256 WGs x 256 threads = 16 batch-groups x 16 WGs.
// (R13/R15 champion geometry.) W pinned in AGPRs (144/lane), c in VGPRs,
// bias folded into acc init. h exchange: TAGGED u32s ((s<<16)|bf16),
// relaxed agent-scope atomics, parity double-buffered, coalesced poll.
// R17 changes vs R15 (all one mechanism: cut chip-wide poll-sweep bytes):
//  (1) SELECTIVE re-poll: per-tile pend[] flags (static-indexed); retries
//      reload only stale tiles (~1-2) instead of all 16.
//  (2) own tile (i == jw) copied from lds_hn locally -- never polled.
//  (3) backoff s_sleep(2) -> s_sleep(1).
#define TSTEPS 512
#define BATCH  256
#define ISZ    64
#define HSZ    512
#define GSZ    2048
#define NKT    18
#define BG     16
#define ROWU   608          // LDS row length in u16 (584 data + 24 pad)
#define PLANE64 65536       // u64 per parity plane: 256*512/2

typedef __attribute__((ext_vector_type(8))) short short8;
typedef __attribute__((ext_vector_type(4))) float f32x4;
typedef __attribute__((ext_vector_type(4))) unsigned int u32x4;
typedef unsigned long long u64t;

static __device__ __forceinline__ unsigned short f2bf(float f) {
    unsigned int u = __float_as_uint(f);
    return (unsigned short)((u + 0x7fffu + ((u >> 16) & 1u)) >> 16);  // RNE
}
static __device__ __forceinline__ float sig_(float x) {
    return 1.0f / (1.0f + __expf(-x));
}
static __device__ __forceinline__ float tanh_(float x) {
    float e = __expf(-2.0f * fabsf(x));
    float t = (1.0f - e) / (1.0f + e);
    return copysignf(t, x);
}
static __device__ __forceinline__ u64t ld_tag64(const u64t* p) {
    return __hip_atomic_load(p, __ATOMIC_RELAXED, __HIP_MEMORY_SCOPE_AGENT);
}
static __device__ __forceinline__ void st_tag64(u64t* p, u64t v) {
    __hip_atomic_store(p, v, __ATOMIC_RELAXED, __HIP_MEMORY_SCOPE_AGENT);
}

// Pack W = [R | kernel^T] (fp32) into bf16 MFMA A-fragment order.
// Frag t = ((jj*8 + m)*18 + kt)*64 + lane; row r = 16m + (lane&15);
// gate q = r&3; hco = r>>2; global row = q*512 + jj*32 + hco.  (unchanged)
__global__ void pack_w(const float* __restrict__ R, const float* __restrict__ Kin,
                       unsigned short* __restrict__ wpack)
{
    const int t  = blockIdx.x * 256 + threadIdx.x;
    const int l  = t & 63;
    const int kt = (t >> 6) % NKT;
    const int m  = (t / (64 * NKT)) & 7;
    const int jj = t / (64 * NKT * 8);
    const int r   = 16 * m + (l & 15);
    const int q   = r & 3;
    const int hco = r >> 2;
    const int grow  = q * HSZ + jj * 32 + hco;
    const int kbase = kt * 32 + (l >> 4) * 8;
    unsigned int pk[4];
#pragma unroll
    for (int p = 0; p < 4; ++p) {
        const int k0 = kbase + 2 * p;
        const int k1 = k0 + 1;
        const float f0 = (k0 < HSZ) ? R[(size_t)grow * HSZ + k0]
                                    : Kin[(size_t)(k0 - HSZ) * GSZ + grow];
        const float f1 = (k1 < HSZ) ? R[(size_t)grow * HSZ + k1]
                                    : Kin[(size_t)(k1 - HSZ) * GSZ + grow];
        pk[p] = (unsigned)f2bf(f0) | ((unsigned)f2bf(f1) << 16);
    }
    uint4 v = make_uint4(pk[0], pk[1], pk[2], pk[3]);
    *reinterpret_cast<uint4*>(wpack + (size_t)t * 8) = v;
}

// Zero tagged h buffer each launch (tag 0 matches no step >= 1): replay-safe.
__global__ void zero_tags(u32x4* __restrict__ hb) {
    u32x4 z = {0u, 0u, 0u, 0u};
    hb[blockIdx.x * 256 + threadIdx.x] = z;
}

__global__ __launch_bounds__(256, 1) void lstm_persist(
    const unsigned short* __restrict__ wpack,
    const float* __restrict__ input_seq,
    const float* __restrict__ bias,
    unsigned int* __restrict__ tbuf,     // [2 parity][256 b][512 col] tagged u32
    float* __restrict__ hlast)
{
    __shared__ __align__(16) unsigned short lds_B[16][ROWU];  // [batch][k]
    __shared__ __align__(16) unsigned short lds_hn[16][40];   // new-h staging
    const int tid = threadIdx.x;
    const int bid = blockIdx.x;          // 256 WGs
    const int gi = bid & 15;             // group; members bid≡gi (mod 16) share XCD
    const int jw = bid >> 4;             // h-col window [jw*32, +32)
    const int jj = jw;                   // gate-slice index (0..15)

    const int w  = tid >> 6;             // wave 0..3
    const int l  = tid & 63;
    const int bb = l & 15;
    const int lg = l >> 4;
    const int m0 = 2 * w, m1 = 2 * w + 1;   // 2 M-tiles per wave (8 per WG)

    // ---- one-time: W fragments -> registers, PINNED into AGPRs (144) ----
    short8 wA[NKT], wB[NKT];
#pragma unroll
    for (int kt = 0; kt < NKT; ++kt) {
        wA[kt] = *reinterpret_cast<const short8*>(
            wpack + (((size_t)(jj * 8 + m0) * NKT + kt) * 64 + l) * 8);
        wB[kt] = *reinterpret_cast<const short8*>(
            wpack + (((size_t)(jj * 8 + m1) * NKT + kt) * 64 + l) * 8);
    }
#pragma unroll
    for (int kt = 0; kt < NKT; ++kt) {
        asm volatile("" : "+a"(wA[kt]));
        asm volatile("" : "+a"(wB[kt]));
    }
    const int hc0 = 4 * m0 + lg, hc1 = 4 * m1 + lg;   // h-col within slice
    const int gh0 = jj * 32 + hc0, gh1 = jj * 32 + hc1;
    float bs0[4], bs1[4];
#pragma unroll
    for (int qg = 0; qg < 4; ++qg) {
        bs0[qg] = bias[qg * HSZ + gh0];
        bs1[qg] = bias[qg * HSZ + gh1];
    }

    float c0 = 0.f, c1 = 0.f;

    // x staging: thread (sb, sc) loads float4 -> 4 bf16 at cols sc*4
    const int sb = tid & 15, sc = tid >> 4;          // sc in [0,16)
    const float* xbase = input_seq + (size_t)(gi * BG + sb) * (TSTEPS * ISZ) + sc * 4;
    float4 xr = *reinterpret_cast<const float4*>(xbase);

    const u64t* const hb0 = reinterpret_cast<const u64t*>(tbuf);
    const u64t* const hb1 = reinterpret_cast<const u64t*>(tbuf) + PLANE64;
    // coalesced consumer mapping: row rr = tid>>4, chunk cch = tid&15;
    // tile i's load: u64 index i*16 + cch (128B contiguous per 16-lane phase).
    const int rr = tid >> 4, cch = tid & 15;
    const size_t csrc = (size_t)(gi * BG + rr) * 256 + cch;   // u64 idx
    // producer mapping: thread (b_, pr): col = jw*32 + pr*2 (+1) -> 1 u64
    const int b_ = tid >> 4, pr = tid & 15;
    const size_t pdst = ((size_t)(gi * BG + b_) * HSZ + jw * 32 + pr * 2) >> 1;

    for (int s = 0; s < TSTEPS; ++s) {
        // stage x(s); prefetch x(s+1)
        {
            uint2 px;
            px.x = (unsigned)f2bf(xr.x) | ((unsigned)f2bf(xr.y) << 16);
            px.y = (unsigned)f2bf(xr.z) | ((unsigned)f2bf(xr.w) << 16);
            *reinterpret_cast<uint2*>(&lds_B[sb][HSZ + sc * 4]) = px;
            if (s + 1 < TSTEPS)
                xr = *reinterpret_cast<const float4*>(xbase + (size_t)(s + 1) * ISZ);
        }
        // ---- acquire h(s): selective tagged poll (only stale tiles retried);
        //      own tile (i == jw) comes from lds_hn, never from the fabric ----
        if (s > 0) {
            const u64t* src = ((s & 1) ? hb1 : hb0) + csrc;
            const u64t want = ((u64t)(unsigned)s << 48) | ((u64t)(unsigned)s << 16);
            u64t v[16];
            bool pend[16];
#pragma unroll
            for (int i = 0; i < 16; ++i) pend[i] = (i != jw);
            bool first = true;
            bool any;
            do {
                if (!first) __builtin_amdgcn_s_sleep(1);
                first = false;
                any = false;
#pragma unroll
                for (int i = 0; i < 16; ++i) {
                    if (pend[i]) {
                        v[i] = ld_tag64(src + (size_t)i * 16);
                        pend[i] = ((v[i] & 0xFFFF0000FFFF0000ull) != want);
                        any = any || pend[i];
                    }
                }
            } while (any);
#pragma unroll
            for (int i = 0; i < 16; ++i) {
                if (i != jw) {
                    const unsigned d = (unsigned)(v[i] & 0xFFFFu) |
                                       ((unsigned)(v[i] >> 16) & 0xFFFF0000u);
                    *reinterpret_cast<unsigned*>(&lds_B[rr][i * 32 + cch * 2]) = d;
                }
            }
            // own tile: local copy from lds_hn (h(s) of this WG's 32 cols)
            {
                const unsigned own =
                    *reinterpret_cast<const unsigned*>(&lds_hn[b_][pr * 2]);
                *reinterpret_cast<unsigned*>(&lds_B[b_][jw * 32 + pr * 2]) = own;
            }
        } else {
#pragma unroll
            for (int i = 0; i < 16; ++i)
                *reinterpret_cast<unsigned*>(&lds_B[rr][i * 32 + cch * 2]) = 0u;
        }
        __syncthreads();   // B: staging complete

        // ---- MFMA: acc initialized with bias ----
        f32x4 acc0 = {bs0[0], bs0[1], bs0[2], bs0[3]};
        f32x4 acc1 = {bs1[0], bs1[1], bs1[2], bs1[3]};
#pragma unroll
        for (int kt = 0; kt < NKT; ++kt) {
            const short8 bf = *reinterpret_cast<const short8*>(
                &lds_B[bb][kt * 32 + lg * 8]);
            acc0 = __builtin_amdgcn_mfma_f32_16x16x32_bf16(wA[kt], bf, acc0, 0, 0, 0);
            acc1 = __builtin_amdgcn_mfma_f32_16x16x32_bf16(wB[kt], bf, acc1, 0, 0, 0);
        }

        // ---- lane-local cell update ----
        const float fg0 = sig_(acc0[0]);
        const float ig0 = sig_(acc0[1]);
        const float cp0 = tanh_(acc0[2]);
        const float og0 = sig_(acc0[3]);
        c0 = fg0 * c0 + ig0 * cp0;
        const float h0v = og0 * tanh_(c0);
        const float fg1 = sig_(acc1[0]);
        const float ig1 = sig_(acc1[1]);
        const float cp1 = tanh_(acc1[2]);
        const float og1 = sig_(acc1[3]);
        c1 = fg1 * c1 + ig1 * cp1;
        const float h1v = og1 * tanh_(c1);

        if (s == TSTEPS - 1) {
            hlast[(size_t)(gi * BG + bb) * HSZ + gh0] = h0v;
            hlast[(size_t)(gi * BG + bb) * HSZ + gh1] = h1v;
            break;
        }
        // stage new h into LDS (slice window of 32 cols)
        lds_hn[bb][hc0] = f2bf(h0v);
        lds_hn[bb][hc1] = f2bf(h1v);
        __syncthreads();   // C: lds_hn ready; lds_B MFMA reads done

        // ---- publish h(s+1): coalesced tagged u64 atomic stores ----
        {
            const unsigned h2 = *reinterpret_cast<const unsigned*>(&lds_hn[b_][pr * 2]);
            const unsigned t16 = (unsigned)(s + 1) << 16;
            const unsigned lo = (h2 & 0xFFFFu) | t16;
            const unsigned hi = (h2 >> 16) | t16;
            const u64t tagged = ((u64t)hi << 32) | (u64t)lo;
            u64t* dst = (u64t*)(tbuf) + (size_t)((s + 1) & 1) * PLANE64 + pdst;
            st_tag64(dst, tagged);
        }
    }
}

// out[b] = h_last[b,:] . Wout + bout
__global__ void out_kernel(const float* __restrict__ hlast,
                           const float* __restrict__ wout,
                           const float* __restrict__ bout,
                           float* __restrict__ out)
{
    const int b = blockIdx.x;
    const int l = threadIdx.x;
    float p = 0.f;
    for (int k = l; k < HSZ; k += 64)
        p += hlast[(size_t)b * HSZ + k] * wout[k];
    for (int off = 32; off > 0; off >>= 1)
        p += __shfl_down(p, off, 64);
    if (l == 0) out[b] = p + bout[0];
}

extern "C" void kernel_launch(void* const* d_in, const int* in_sizes, int n_in,
                              void* d_out, int out_size, void* d_ws, size_t ws_size,
                              hipStream_t stream) {
    const float* input_seq = (const float*)d_in[0];
    const float* Kin       = (const float*)d_in[1];
    const float* R         = (const float*)d_in[2];
    const float* bias      = (const float*)d_in[3];
    const float* Wout      = (const float*)d_in[4];
    const float* bout      = (const float*)d_in[5];
    float* out = (float*)d_out;

    char* ws = (char*)d_ws;
    unsigned short* wpack = (unsigned short*)(ws);                    // 2,359,296 B
    unsigned int* tbuf    = (unsigned int*)(ws + 2359296);            // 1,048,576 B
    float* hlast          = (float*)(ws + 2359296 + 1048576);         //   524,288 B

    zero_tags<<<dim3(256), dim3(256), 0, stream>>>((u32x4*)tbuf);
    pack_w<<<dim3(576), dim3(256), 0, stream>>>(R, Kin, wpack);
    lstm_persist<<<dim3(256), dim3(256), 0, stream>>>(
        wpack, input_seq, bias, tbuf, hlast);
    out_kernel<<<dim3(256), dim3(64), 0, stream>>>(hlast, Wout, bout, out);
}

// Round 18
// 1175.630 us; speedup vs baseline: 2.3106x; 2.3106x over previous
//
#include <hip/hip_runtime.h>

// LSTM: B=256, T=512, I=64, H=512, G=4H=2048.
// gates = W @ [h; x], W = [R | kernel^T], K = 576.
// Persistent kernel: 256 WGs x 256 threads = 16 batch-groups x 16 WGs.
// (R13/R15 champion.) W pinned in AGPRs (144/lane), c in VGPRs, bias folded
// into acc init. h exchange: TAGGED u32s ((s<<16)|bf16), relaxed agent-scope
// atomics, parity double-buffered, coalesced 16-load burst poll (full MLP).
// R18 change (one mechanism): KILL barrier C + per-wave early publish.
//  - lds_B becomes parity double-buffered [2][16][ROWU]; single
//    __syncthreads per step (staging(s+1) writes plane ~p while stragglers
//    read plane p; barrier B orders MFMA(s) before staging(s+2)).
//  - publish: pack bf16(h0)|bf16(h1)<<16 per lane, 2x ds_bpermute moves the
//    col-pair to publisher lane (b=l>>2, pp=l&3 -> 32B-contiguous per 4
//    lanes); each wave publishes right after ITS cell (no lds_hn, no C,
//    earlier release -> less producer skew).
#define TSTEPS 512
#define BATCH  256
#define ISZ    64
#define HSZ    512
#define GSZ    2048
#define NKT    18
#define BG     16
#define ROWU   608          // LDS row length in u16 (584 data + 24 pad)
#define PLANE64 65536       // u64 per parity plane: 256*512/2

typedef __attribute__((ext_vector_type(8))) short short8;
typedef __attribute__((ext_vector_type(4))) float f32x4;
typedef __attribute__((ext_vector_type(4))) unsigned int u32x4;
typedef unsigned long long u64t;

static __device__ __forceinline__ unsigned short f2bf(float f) {
    unsigned int u = __float_as_uint(f);
    return (unsigned short)((u + 0x7fffu + ((u >> 16) & 1u)) >> 16);  // RNE
}
static __device__ __forceinline__ float sig_(float x) {
    return 1.0f / (1.0f + __expf(-x));
}
static __device__ __forceinline__ float tanh_(float x) {
    float e = __expf(-2.0f * fabsf(x));
    float t = (1.0f - e) / (1.0f + e);
    return copysignf(t, x);
}
static __device__ __forceinline__ u64t ld_tag64(const u64t* p) {
    return __hip_atomic_load(p, __ATOMIC_RELAXED, __HIP_MEMORY_SCOPE_AGENT);
}
static __device__ __forceinline__ void st_tag64(u64t* p, u64t v) {
    __hip_atomic_store(p, v, __ATOMIC_RELAXED, __HIP_MEMORY_SCOPE_AGENT);
}

// Pack W = [R | kernel^T] (fp32) into bf16 MFMA A-fragment order. (unchanged)
__global__ void pack_w(const float* __restrict__ R, const float* __restrict__ Kin,
                       unsigned short* __restrict__ wpack)
{
    const int t  = blockIdx.x * 256 + threadIdx.x;
    const int l  = t & 63;
    const int kt = (t >> 6) % NKT;
    const int m  = (t / (64 * NKT)) & 7;
    const int jj = t / (64 * NKT * 8);
    const int r   = 16 * m + (l & 15);
    const int q   = r & 3;
    const int hco = r >> 2;
    const int grow  = q * HSZ + jj * 32 + hco;
    const int kbase = kt * 32 + (l >> 4) * 8;
    unsigned int pk[4];
#pragma unroll
    for (int p = 0; p < 4; ++p) {
        const int k0 = kbase + 2 * p;
        const int k1 = k0 + 1;
        const float f0 = (k0 < HSZ) ? R[(size_t)grow * HSZ + k0]
                                    : Kin[(size_t)(k0 - HSZ) * GSZ + grow];
        const float f1 = (k1 < HSZ) ? R[(size_t)grow * HSZ + k1]
                                    : Kin[(size_t)(k1 - HSZ) * GSZ + grow];
        pk[p] = (unsigned)f2bf(f0) | ((unsigned)f2bf(f1) << 16);
    }
    uint4 v = make_uint4(pk[0], pk[1], pk[2], pk[3]);
    *reinterpret_cast<uint4*>(wpack + (size_t)t * 8) = v;
}

// Zero tagged h buffer each launch (tag 0 matches no step >= 1): replay-safe.
__global__ void zero_tags(u32x4* __restrict__ hb) {
    u32x4 z = {0u, 0u, 0u, 0u};
    hb[blockIdx.x * 256 + threadIdx.x] = z;
}

__global__ __launch_bounds__(256, 1) void lstm_persist(
    const unsigned short* __restrict__ wpack,
    const float* __restrict__ input_seq,
    const float* __restrict__ bias,
    unsigned int* __restrict__ tbuf,     // [2 parity][256 b][512 col] tagged u32
    float* __restrict__ hlast)
{
    __shared__ __align__(16) unsigned short lds_B[2][16][ROWU];  // parity planes
    const int tid = threadIdx.x;
    const int bid = blockIdx.x;          // 256 WGs
    const int gi = bid & 15;             // group; members bid≡gi (mod 16) share XCD
    const int jw = bid >> 4;             // h-col window [jw*32, +32)
    const int jj = jw;                   // gate-slice index (0..15)

    const int w  = tid >> 6;             // wave 0..3
    const int l  = tid & 63;
    const int bb = l & 15;
    const int lg = l >> 4;
    const int m0 = 2 * w, m1 = 2 * w + 1;   // 2 M-tiles per wave (8 per WG)

    // ---- one-time: W fragments -> registers, PINNED into AGPRs (144) ----
    short8 wA[NKT], wB[NKT];
#pragma unroll
    for (int kt = 0; kt < NKT; ++kt) {
        wA[kt] = *reinterpret_cast<const short8*>(
            wpack + (((size_t)(jj * 8 + m0) * NKT + kt) * 64 + l) * 8);
        wB[kt] = *reinterpret_cast<const short8*>(
            wpack + (((size_t)(jj * 8 + m1) * NKT + kt) * 64 + l) * 8);
    }
#pragma unroll
    for (int kt = 0; kt < NKT; ++kt) {
        asm volatile("" : "+a"(wA[kt]));
        asm volatile("" : "+a"(wB[kt]));
    }
    const int hc0 = 4 * m0 + lg, hc1 = 4 * m1 + lg;   // h-col within slice
    const int gh0 = jj * 32 + hc0, gh1 = jj * 32 + hc1;
    float bs0[4], bs1[4];
#pragma unroll
    for (int qg = 0; qg < 4; ++qg) {
        bs0[qg] = bias[qg * HSZ + gh0];
        bs1[qg] = bias[qg * HSZ + gh1];
    }

    float c0 = 0.f, c1 = 0.f;

    // x staging: thread (sb, sc) loads float4 -> 4 bf16 at cols sc*4
    const int sb = tid & 15, sc = tid >> 4;          // sc in [0,16)
    const float* xbase = input_seq + (size_t)(gi * BG + sb) * (TSTEPS * ISZ) + sc * 4;
    float4 xr = *reinterpret_cast<const float4*>(xbase);

    const u64t* const hb0 = reinterpret_cast<const u64t*>(tbuf);
    const u64t* const hb1 = reinterpret_cast<const u64t*>(tbuf) + PLANE64;
    // coalesced consumer mapping: row rr = tid>>4, chunk cch = tid&15;
    // tile i's load: u64 index i*16 + cch (128B contiguous per 16-lane phase).
    const int rr = tid >> 4, cch = tid & 15;
    const size_t csrc = (size_t)(gi * BG + rr) * 256 + cch;   // u64 idx
    // ---- publisher mapping (per wave, in-wave redistribution) ----
    // lane l publishes batch pb = l>>2, col-pair pp = l&3 of cols [8w, 8w+8):
    // global u64 idx = (gi*16+pb)*256 + jw*16 + 4w + pp. Sources are lanes
    // (lg<<4)|pb with lg = (pp&1)*2 (+1), chain h0 if pp<2 else h1.
    const int pb = l >> 2, pp = l & 3;
    const size_t pdst = (size_t)(gi * BG + pb) * 256 + jw * 16 + 4 * w + pp;
    const int lgs = (pp & 1) * 2;
    const int idx1 = (((lgs) << 4) | pb) << 2;       // byte index for bpermute
    const int idx2 = (((lgs + 1) << 4) | pb) << 2;
    const bool hiHalf = (pp >= 2);                   // chain h1 lives in hi 16

    for (int s = 0; s < TSTEPS; ++s) {
        const int pl = s & 1;
        // stage x(s) into plane pl; prefetch x(s+1)
        {
            uint2 px;
            px.x = (unsigned)f2bf(xr.x) | ((unsigned)f2bf(xr.y) << 16);
            px.y = (unsigned)f2bf(xr.z) | ((unsigned)f2bf(xr.w) << 16);
            *reinterpret_cast<uint2*>(&lds_B[pl][sb][HSZ + sc * 4]) = px;
            if (s + 1 < TSTEPS)
                xr = *reinterpret_cast<const float4*>(xbase + (size_t)(s + 1) * ISZ);
        }
        // ---- acquire h(s): unconditional 16-load burst poll (full MLP) ----
        if (s > 0) {
            const u64t* src = ((s & 1) ? hb1 : hb0) + csrc;
            const u64t want = ((u64t)(unsigned)s << 48) | ((u64t)(unsigned)s << 16);
            u64t v[16];
            bool ok;
            bool first = true;
            do {
                if (!first) __builtin_amdgcn_s_sleep(2);
                first = false;
                ok = true;
#pragma unroll
                for (int i = 0; i < 16; ++i)
                    v[i] = ld_tag64(src + (size_t)i * 16);
#pragma unroll
                for (int i = 0; i < 16; ++i)
                    ok = ok && ((v[i] & 0xFFFF0000FFFF0000ull) == want);
            } while (!ok);
#pragma unroll
            for (int i = 0; i < 16; ++i) {
                const unsigned d = (unsigned)(v[i] & 0xFFFFu) |
                                   ((unsigned)(v[i] >> 16) & 0xFFFF0000u);
                *reinterpret_cast<unsigned*>(&lds_B[pl][rr][i * 32 + cch * 2]) = d;
            }
        } else {
#pragma unroll
            for (int i = 0; i < 16; ++i)
                *reinterpret_cast<unsigned*>(&lds_B[pl][rr][i * 32 + cch * 2]) = 0u;
        }
        __syncthreads();   // B: staging complete (the ONLY barrier per step)

        // ---- MFMA: acc initialized with bias ----
        f32x4 acc0 = {bs0[0], bs0[1], bs0[2], bs0[3]};
        f32x4 acc1 = {bs1[0], bs1[1], bs1[2], bs1[3]};
#pragma unroll
        for (int kt = 0; kt < NKT; ++kt) {
            const short8 bf = *reinterpret_cast<const short8*>(
                &lds_B[pl][bb][kt * 32 + lg * 8]);
            acc0 = __builtin_amdgcn_mfma_f32_16x16x32_bf16(wA[kt], bf, acc0, 0, 0, 0);
            acc1 = __builtin_amdgcn_mfma_f32_16x16x32_bf16(wB[kt], bf, acc1, 0, 0, 0);
        }

        // ---- lane-local cell update ----
        const float fg0 = sig_(acc0[0]);
        const float ig0 = sig_(acc0[1]);
        const float cp0 = tanh_(acc0[2]);
        const float og0 = sig_(acc0[3]);
        c0 = fg0 * c0 + ig0 * cp0;
        const float h0v = og0 * tanh_(c0);
        const float fg1 = sig_(acc1[0]);
        const float ig1 = sig_(acc1[1]);
        const float cp1 = tanh_(acc1[2]);
        const float og1 = sig_(acc1[3]);
        c1 = fg1 * c1 + ig1 * cp1;
        const float h1v = og1 * tanh_(c1);

        if (s == TSTEPS - 1) {
            hlast[(size_t)(gi * BG + bb) * HSZ + gh0] = h0v;
            hlast[(size_t)(gi * BG + bb) * HSZ + gh1] = h1v;
            break;
        }

        // ---- per-wave early publish: in-wave redistribution + tagged u64 ----
        {
            const unsigned pk = (unsigned)f2bf(h0v) | ((unsigned)f2bf(h1v) << 16);
            const unsigned r1 = (unsigned)__builtin_amdgcn_ds_bpermute(idx1, (int)pk);
            const unsigned r2 = (unsigned)__builtin_amdgcn_ds_bpermute(idx2, (int)pk);
            const unsigned val1 = hiHalf ? (r1 >> 16) : (r1 & 0xFFFFu);
            const unsigned val2 = hiHalf ? (r2 >> 16) : (r2 & 0xFFFFu);
            const unsigned t16 = (unsigned)(s + 1) << 16;
            const u64t tagged = ((u64t)(val2 | t16) << 32) | (u64t)(val1 | t16);
            u64t* dst = (u64t*)(tbuf) + (size_t)((s + 1) & 1) * PLANE64 + pdst;
            st_tag64(dst, tagged);
        }
    }
}

// out[b] = h_last[b,:] . Wout + bout
__global__ void out_kernel(const float* __restrict__ hlast,
                           const float* __restrict__ wout,
                           const float* __restrict__ bout,
                           float* __restrict__ out)
{
    const int b = blockIdx.x;
    const int l = threadIdx.x;
    float p = 0.f;
    for (int k = l; k < HSZ; k += 64)
        p += hlast[(size_t)b * HSZ + k] * wout[k];
    for (int off = 32; off > 0; off >>= 1)
        p += __shfl_down(p, off, 64);
    if (l == 0) out[b] = p + bout[0];
}

extern "C" void kernel_launch(void* const* d_in, const int* in_sizes, int n_in,
                              void* d_out, int out_size, void* d_ws, size_t ws_size,
                              hipStream_t stream) {
    const float* input_seq = (const float*)d_in[0];
    const float* Kin       = (const float*)d_in[1];
    const float* R         = (const float*)d_in[2];
    const float* bias      = (const float*)d_in[3];
    const float* Wout      = (const float*)d_in[4];
    const float* bout      = (const float*)d_in[5];
    float* out = (float*)d_out;

    char* ws = (char*)d_ws;
    unsigned short* wpack = (unsigned short*)(ws);                    // 2,359,296 B
    unsigned int* tbuf    = (unsigned int*)(ws + 2359296);            // 1,048,576 B
    float* hlast          = (float*)(ws + 2359296 + 1048576);         //   524,288 B

    zero_tags<<<dim3(256), dim3(256), 0, stream>>>((u32x4*)tbuf);
    pack_w<<<dim3(576), dim3(256), 0, stream>>>(R, Kin, wpack);
    lstm_persist<<<dim3(256), dim3(256), 0, stream>>>(
        wpack, input_seq, bias, tbuf, hlast);
    out_kernel<<<dim3(256), dim3(64), 0, stream>>>(hlast, Wout, bout, out);
}

// Round 19
// 1128.648 us; speedup vs baseline: 2.4068x; 1.0416x over previous
//
#include <hip/hip_runtime.h>

// LSTM: B=256, T=512, I=64, H=512, G=4H=2048.
// gates = W @ [h; x], W = [R | kernel^T], K = 576.
// Persistent kernel: 256 WGs x 256 threads = 16 batch-groups x 16 WGs.
// (R13/R15 champion geometry.) W pinned in AGPRs (144/lane), c in VGPRs,
// bias folded into acc init. h exchange: TAGGED u32s ((s<<16)|bf16),
// relaxed agent-scope atomics, parity double-buffered, coalesced
// 16-load burst poll (full MLP).
// R19 single change vs R15: retry backoff s_sleep(2) -> s_sleep(10).
// Mechanism: detection-retry VARIANCE (not mean) is the binding term of the
// max-over-16 skew cascade; a ~640-cyc backoff makes the 2nd sweep land
// past the arrival window -> two-point detection distribution, sigma
// collapses, max-over-16 tax shrinks toward the mean.
#define TSTEPS 512
#define BATCH  256
#define ISZ    64
#define HSZ    512
#define GSZ    2048
#define NKT    18
#define BG     16
#define ROWU   608          // LDS row length in u16 (584 data + 24 pad)
#define PLANE64 65536       // u64 per parity plane: 256*512/2

typedef __attribute__((ext_vector_type(8))) short short8;
typedef __attribute__((ext_vector_type(4))) float f32x4;
typedef __attribute__((ext_vector_type(4))) unsigned int u32x4;
typedef unsigned long long u64t;

static __device__ __forceinline__ unsigned short f2bf(float f) {
    unsigned int u = __float_as_uint(f);
    return (unsigned short)((u + 0x7fffu + ((u >> 16) & 1u)) >> 16);  // RNE
}
static __device__ __forceinline__ float sig_(float x) {
    return 1.0f / (1.0f + __expf(-x));
}
static __device__ __forceinline__ float tanh_(float x) {
    float e = __expf(-2.0f * fabsf(x));
    float t = (1.0f - e) / (1.0f + e);
    return copysignf(t, x);
}
static __device__ __forceinline__ u64t ld_tag64(const u64t* p) {
    return __hip_atomic_load(p, __ATOMIC_RELAXED, __HIP_MEMORY_SCOPE_AGENT);
}
static __device__ __forceinline__ void st_tag64(u64t* p, u64t v) {
    __hip_atomic_store(p, v, __ATOMIC_RELAXED, __HIP_MEMORY_SCOPE_AGENT);
}

// Pack W = [R | kernel^T] (fp32) into bf16 MFMA A-fragment order.
// Frag t = ((jj*8 + m)*18 + kt)*64 + lane; row r = 16m + (lane&15);
// gate q = r&3; hco = r>>2; global row = q*512 + jj*32 + hco.  (unchanged)
__global__ void pack_w(const float* __restrict__ R, const float* __restrict__ Kin,
                       unsigned short* __restrict__ wpack)
{
    const int t  = blockIdx.x * 256 + threadIdx.x;
    const int l  = t & 63;
    const int kt = (t >> 6) % NKT;
    const int m  = (t / (64 * NKT)) & 7;
    const int jj = t / (64 * NKT * 8);
    const int r   = 16 * m + (l & 15);
    const int q   = r & 3;
    const int hco = r >> 2;
    const int grow  = q * HSZ + jj * 32 + hco;
    const int kbase = kt * 32 + (l >> 4) * 8;
    unsigned int pk[4];
#pragma unroll
    for (int p = 0; p < 4; ++p) {
        const int k0 = kbase + 2 * p;
        const int k1 = k0 + 1;
        const float f0 = (k0 < HSZ) ? R[(size_t)grow * HSZ + k0]
                                    : Kin[(size_t)(k0 - HSZ) * GSZ + grow];
        const float f1 = (k1 < HSZ) ? R[(size_t)grow * HSZ + k1]
                                    : Kin[(size_t)(k1 - HSZ) * GSZ + grow];
        pk[p] = (unsigned)f2bf(f0) | ((unsigned)f2bf(f1) << 16);
    }
    uint4 v = make_uint4(pk[0], pk[1], pk[2], pk[3]);
    *reinterpret_cast<uint4*>(wpack + (size_t)t * 8) = v;
}

// Zero tagged h buffer each launch (tag 0 matches no step >= 1): replay-safe.
__global__ void zero_tags(u32x4* __restrict__ hb) {
    u32x4 z = {0u, 0u, 0u, 0u};
    hb[blockIdx.x * 256 + threadIdx.x] = z;
}

__global__ __launch_bounds__(256, 1) void lstm_persist(
    const unsigned short* __restrict__ wpack,
    const float* __restrict__ input_seq,
    const float* __restrict__ bias,
    unsigned int* __restrict__ tbuf,     // [2 parity][256 b][512 col] tagged u32
    float* __restrict__ hlast)
{
    __shared__ __align__(16) unsigned short lds_B[16][ROWU];  // [batch][k]
    __shared__ __align__(16) unsigned short lds_hn[16][40];   // new-h staging
    const int tid = threadIdx.x;
    const int bid = blockIdx.x;          // 256 WGs
    const int gi = bid & 15;             // group; members bid≡gi (mod 16) share XCD
    const int jw = bid >> 4;             // h-col window [jw*32, +32)
    const int jj = jw;                   // gate-slice index (0..15)

    const int w  = tid >> 6;             // wave 0..3
    const int l  = tid & 63;
    const int bb = l & 15;
    const int lg = l >> 4;
    const int m0 = 2 * w, m1 = 2 * w + 1;   // 2 M-tiles per wave (8 per WG)

    // ---- one-time: W fragments -> registers, PINNED into AGPRs (144) ----
    short8 wA[NKT], wB[NKT];
#pragma unroll
    for (int kt = 0; kt < NKT; ++kt) {
        wA[kt] = *reinterpret_cast<const short8*>(
            wpack + (((size_t)(jj * 8 + m0) * NKT + kt) * 64 + l) * 8);
        wB[kt] = *reinterpret_cast<const short8*>(
            wpack + (((size_t)(jj * 8 + m1) * NKT + kt) * 64 + l) * 8);
    }
#pragma unroll
    for (int kt = 0; kt < NKT; ++kt) {
        asm volatile("" : "+a"(wA[kt]));
        asm volatile("" : "+a"(wB[kt]));
    }
    const int hc0 = 4 * m0 + lg, hc1 = 4 * m1 + lg;   // h-col within slice
    const int gh0 = jj * 32 + hc0, gh1 = jj * 32 + hc1;
    float bs0[4], bs1[4];
#pragma unroll
    for (int qg = 0; qg < 4; ++qg) {
        bs0[qg] = bias[qg * HSZ + gh0];
        bs1[qg] = bias[qg * HSZ + gh1];
    }

    float c0 = 0.f, c1 = 0.f;

    // x staging: thread (sb, sc) loads float4 -> 4 bf16 at cols sc*4
    const int sb = tid & 15, sc = tid >> 4;          // sc in [0,16)
    const float* xbase = input_seq + (size_t)(gi * BG + sb) * (TSTEPS * ISZ) + sc * 4;
    float4 xr = *reinterpret_cast<const float4*>(xbase);

    const u64t* const hb0 = reinterpret_cast<const u64t*>(tbuf);
    const u64t* const hb1 = reinterpret_cast<const u64t*>(tbuf) + PLANE64;
    // coalesced consumer mapping: row rr = tid>>4, chunk cch = tid&15;
    // 16 loads stride 16 u64 (128B contiguous per 16-lane phase).
    const int rr = tid >> 4, cch = tid & 15;
    const size_t csrc = (size_t)(gi * BG + rr) * 256 + cch;   // u64 idx
    // producer mapping: thread (b_, pr): col = jw*32 + pr*2 (+1) -> 1 u64
    const int b_ = tid >> 4, pr = tid & 15;
    const size_t pdst = ((size_t)(gi * BG + b_) * HSZ + jw * 32 + pr * 2) >> 1;

    for (int s = 0; s < TSTEPS; ++s) {
        // stage x(s); prefetch x(s+1)
        {
            uint2 px;
            px.x = (unsigned)f2bf(xr.x) | ((unsigned)f2bf(xr.y) << 16);
            px.y = (unsigned)f2bf(xr.z) | ((unsigned)f2bf(xr.w) << 16);
            *reinterpret_cast<uint2*>(&lds_B[sb][HSZ + sc * 4]) = px;
            if (s + 1 < TSTEPS)
                xr = *reinterpret_cast<const float4*>(xbase + (size_t)(s + 1) * ISZ);
        }
        // ---- acquire h(s): burst poll; LONG backoff on miss (variance fix) ----
        if (s > 0) {
            const u64t* src = ((s & 1) ? hb1 : hb0) + csrc;
            const u64t want = ((u64t)(unsigned)s << 48) | ((u64t)(unsigned)s << 16);
            u64t v[16];
            bool ok;
            bool first = true;
            do {
                if (!first) __builtin_amdgcn_s_sleep(10);   // ~640 cyc backoff
                first = false;
                ok = true;
#pragma unroll
                for (int i = 0; i < 16; ++i)
                    v[i] = ld_tag64(src + (size_t)i * 16);
#pragma unroll
                for (int i = 0; i < 16; ++i)
                    ok = ok && ((v[i] & 0xFFFF0000FFFF0000ull) == want);
            } while (!ok);
#pragma unroll
            for (int i = 0; i < 16; ++i) {
                const unsigned d = (unsigned)(v[i] & 0xFFFFu) |
                                   ((unsigned)(v[i] >> 16) & 0xFFFF0000u);
                *reinterpret_cast<unsigned*>(&lds_B[rr][i * 32 + cch * 2]) = d;
            }
        } else {
#pragma unroll
            for (int i = 0; i < 16; ++i)
                *reinterpret_cast<unsigned*>(&lds_B[rr][i * 32 + cch * 2]) = 0u;
        }
        __syncthreads();   // B: staging complete

        // ---- MFMA: acc initialized with bias ----
        f32x4 acc0 = {bs0[0], bs0[1], bs0[2], bs0[3]};
        f32x4 acc1 = {bs1[0], bs1[1], bs1[2], bs1[3]};
#pragma unroll
        for (int kt = 0; kt < NKT; ++kt) {
            const short8 bf = *reinterpret_cast<const short8*>(
                &lds_B[bb][kt * 32 + lg * 8]);
            acc0 = __builtin_amdgcn_mfma_f32_16x16x32_bf16(wA[kt], bf, acc0, 0, 0, 0);
            acc1 = __builtin_amdgcn_mfma_f32_16x16x32_bf16(wB[kt], bf, acc1, 0, 0, 0);
        }

        // ---- lane-local cell update ----
        const float fg0 = sig_(acc0[0]);
        const float ig0 = sig_(acc0[1]);
        const float cp0 = tanh_(acc0[2]);
        const float og0 = sig_(acc0[3]);
        c0 = fg0 * c0 + ig0 * cp0;
        const float h0v = og0 * tanh_(c0);
        const float fg1 = sig_(acc1[0]);
        const float ig1 = sig_(acc1[1]);
        const float cp1 = tanh_(acc1[2]);
        const float og1 = sig_(acc1[3]);
        c1 = fg1 * c1 + ig1 * cp1;
        const float h1v = og1 * tanh_(c1);

        if (s == TSTEPS - 1) {
            hlast[(size_t)(gi * BG + bb) * HSZ + gh0] = h0v;
            hlast[(size_t)(gi * BG + bb) * HSZ + gh1] = h1v;
            break;
        }
        // stage new h into LDS (slice window of 32 cols)
        lds_hn[bb][hc0] = f2bf(h0v);
        lds_hn[bb][hc1] = f2bf(h1v);
        __syncthreads();   // C: lds_hn ready; lds_B MFMA reads done

        // ---- publish h(s+1): coalesced tagged u64 atomic stores ----
        {
            const unsigned h2 = *reinterpret_cast<const unsigned*>(&lds_hn[b_][pr * 2]);
            const unsigned t16 = (unsigned)(s + 1) << 16;
            const unsigned lo = (h2 & 0xFFFFu) | t16;
            const unsigned hi = (h2 >> 16) | t16;
            const u64t tagged = ((u64t)hi << 32) | (u64t)lo;
            u64t* dst = (u64t*)(tbuf) + (size_t)((s + 1) & 1) * PLANE64 + pdst;
            st_tag64(dst, tagged);
        }
    }
}

// out[b] = h_last[b,:] . Wout + bout
__global__ void out_kernel(const float* __restrict__ hlast,
                           const float* __restrict__ wout,
                           const float* __restrict__ bout,
                           float* __restrict__ out)
{
    const int b = blockIdx.x;
    const int l = threadIdx.x;
    float p = 0.f;
    for (int k = l; k < HSZ; k += 64)
        p += hlast[(size_t)b * HSZ + k] * wout[k];
    for (int off = 32; off > 0; off >>= 1)
        p += __shfl_down(p, off, 64);
    if (l == 0) out[b] = p + bout[0];
}

extern "C" void kernel_launch(void* const* d_in, const int* in_sizes, int n_in,
                              void* d_out, int out_size, void* d_ws, size_t ws_size,
                              hipStream_t stream) {
    const float* input_seq = (const float*)d_in[0];
    const float* Kin       = (const float*)d_in[1];
    const float* R         = (const float*)d_in[2];
    const float* bias      = (const float*)d_in[3];
    const float* Wout      = (const float*)d_in[4];
    const float* bout      = (const float*)d_in[5];
    float* out = (float*)d_out;

    char* ws = (char*)d_ws;
    unsigned short* wpack = (unsigned short*)(ws);                    // 2,359,296 B
    unsigned int* tbuf    = (unsigned int*)(ws + 2359296);            // 1,048,576 B
    float* hlast          = (float*)(ws + 2359296 + 1048576);         //   524,288 B

    zero_tags<<<dim3(256), dim3(256), 0, stream>>>((u32x4*)tbuf);
    pack_w<<<dim3(576), dim3(256), 0, stream>>>(R, Kin, wpack);
    lstm_persist<<<dim3(256), dim3(256), 0, stream>>>(
        wpack, input_seq, bias, tbuf, hlast);
    out_kernel<<<dim3(256), dim3(64), 0, stream>>>(hlast, Wout, bout, out);
}